// Round 6
// baseline (1877.137 us; speedup 1.0000x reference)
//
#include <hip/hip_runtime.h>
#include <cstdint>

// DimeNet interaction block, MI355X/gfx950.  Round 6.
// Round-5 finding: bilinear pinned at 250us regardless of staging quality;
// WRITE_SIZE 332 MB vs 51 MB nominal -> cross-XCD f32 atomic scatter is the
// round-invariant cost (plus compiler's vmcnt(0)-before-barrier defeats
// cross-barrier prefetch).  Fix: device-built CSR by e_to; each bilinear
// block OWNS 64 destination edges -> accumulate msg in LDS (ds_add_f32),
// one plain store per row.  Zero global atomics.  B-operands read directly
// from fragment-linear Wf in global (L1/L2-hit), so the jj-loop has no
// barriers at all; per-chunk gather is register-prefetched in the shadow of
// the previous chunk's MFMA.
//
// Dtypes: float tensors f32; indices int32; out f32.
// Internals: f16 MFMA operands, fp32 accumulate (absmax 0.031 @ thr 0.165).
// d_out: x_ji written by edge, then bilinear adds its owned rows in place,
//        then post consumes/overwrites.  All row-exclusive, race-free.

#define H 128
#define NB 8
#define NR 6
#define SBC 42
#define LDA 136      // f16 lane pad
#define LDF 132      // f32 lane pad
#define WFRAG 16384  // f16 elems per fragment-linear 128x128 weight

using f16x8 = __attribute__((ext_vector_type(8))) _Float16;
using f32x4 = __attribute__((ext_vector_type(4))) float;

__device__ __forceinline__ float silu_f(float v){
  return v / (1.f + __expf(-v));
}
__device__ __forceinline__ f16x8 pack8(float4 a, float4 b){
  f16x8 h;
  h[0]=(_Float16)a.x; h[1]=(_Float16)a.y; h[2]=(_Float16)a.z; h[3]=(_Float16)a.w;
  h[4]=(_Float16)b.x; h[5]=(_Float16)b.y; h[6]=(_Float16)b.z; h[7]=(_Float16)b.w;
  return h;
}

// ---------------- prep: weights -> MFMA-B-fragment-linear f16 ----------------
__global__ void prep_kernel(const float* __restrict__ w_from,
                            const float* __restrict__ w_to,
                            const float* __restrict__ rb_w,
                            const float* __restrict__ lin_w,
                            const float* __restrict__ ra_w,
                            const float* __restrict__ Wb,
                            _Float16* __restrict__ wf,
                            _Float16* __restrict__ Wf)
{
  int idx = blockIdx.x*256 + threadIdx.x;
  if (blockIdx.x < 72){                 // 72*256 == 9*2048
    int m = idx >> 11, c = idx & 2047;
    int nt = c >> 8, kk = (c>>6)&3, l = c&63, q = l>>4, l15 = l&15;
    const float* src;
    switch(m){
      case 0: src = w_from;       break;
      case 1: src = w_to;         break;
      case 2: src = rb_w;         break;
      case 3: src = rb_w + 16384; break;
      case 4: src = lin_w;        break;
      case 5: src = ra_w;         break;
      case 6: src = ra_w + 16384; break;
      case 7: src = ra_w + 32768; break;
      default: src = ra_w + 49152; break;
    }
    const float* p = src + (size_t)(kk*32 + q*8)*H + nt*16 + l15;
    f16x8 o;
    #pragma unroll
    for (int j=0;j<8;j++) o[j] = (_Float16)p[(size_t)j*H];
    *reinterpret_cast<f16x8*>(wf + (size_t)m*WFRAG + c*8) = o;
  } else {
    int t = idx - 72*256;               // < 16384 (64 blocks)
    int j = t >> 11, c = t & 2047;
    int nt = c >> 8, kk = (c>>6)&3, l = c&63, q = l>>4, l15 = l&15;
    const float4* p = reinterpret_cast<const float4*>(
        Wb + ((size_t)(nt*16+l15)*NB + j)*H + kk*32 + q*8);
    *reinterpret_cast<f16x8*>(Wf + (size_t)j*WFRAG + c*8) = pack8(p[0], p[1]);
  }
}

// ---------------- sbf16: [T,42]@[42,8] -> f16 [T,8] ----------------
__global__ __launch_bounds__(256) void sbf16_kernel(
    const float* __restrict__ sph, const float* __restrict__ w_sbf,
    _Float16* __restrict__ sbf16, int T)
{
  __shared__ float sw[SBC*NB];
  __shared__ float srow[256*SBC];
  int tid = threadIdx.x;
  long long t0 = (long long)blockIdx.x * 256;
  for (int i=tid; i<SBC*NB; i+=256) sw[i] = w_sbf[i];
  long long lim = (long long)T*SBC;
  for (int i=tid; i<256*SBC; i+=256){
    long long idx = t0*SBC + i;
    srow[i] = (idx < lim) ? sph[idx] : 0.f;
  }
  __syncthreads();
  if (t0 + tid < T){
    float acc[NB];
    #pragma unroll
    for (int j=0;j<NB;j++) acc[j]=0.f;
    const float* r = srow + tid*SBC;
    for (int c=0;c<SBC;c++){
      float v = r[c];
      #pragma unroll
      for (int j=0;j<NB;j++) acc[j] += v * sw[c*NB+j];
    }
    f16x8 o;
    #pragma unroll
    for (int j=0;j<NB;j++) o[j] = (_Float16)acc[j];
    *reinterpret_cast<f16x8*>(sbf16 + (t0+tid)*NB) = o;
  }
}

// ---------------- CSR build ----------------
__global__ void zero_kernel(int* __restrict__ cnt, int n){
  int i = blockIdx.x*256 + threadIdx.x;
  if (i < n) cnt[i] = 0;
}
__global__ void hist_kernel(const int* __restrict__ e_to, int* __restrict__ cnt, int T){
  int i = blockIdx.x*256 + threadIdx.x;
  if (i < T) atomicAdd(&cnt[e_to[i]], 1);
}
__global__ void scan1_kernel(const int* __restrict__ cnt, int* __restrict__ incl,
                             int* __restrict__ partials, int n){
  __shared__ int s[256];
  int t = threadIdx.x, i = blockIdx.x*256 + t;
  int v = (i < n) ? cnt[i] : 0;
  s[t] = v; __syncthreads();
  for (int off=1; off<256; off<<=1){
    int u = (t >= off) ? s[t-off] : 0; __syncthreads();
    s[t] += u; __syncthreads();
  }
  if (i < n) incl[i] = s[t];
  if (t == 255) partials[blockIdx.x] = s[255];
}
__global__ void scan2_kernel(int* __restrict__ partials, int nb){
  __shared__ int s[512];
  int t = threadIdx.x;
  int v = (t < nb) ? partials[t] : 0;
  s[t] = v; __syncthreads();
  for (int off=1; off<512; off<<=1){
    int u = (t >= off) ? s[t-off] : 0; __syncthreads();
    s[t] += u; __syncthreads();
  }
  if (t < nb) partials[t] = s[t] - v;   // exclusive
}
__global__ void scan3_kernel(const int* __restrict__ incl, const int* __restrict__ cnt,
                             const int* __restrict__ partials, int* __restrict__ row_ptr,
                             int* __restrict__ pos, int E, int T){
  int i = blockIdx.x*256 + threadIdx.x;
  if (i < E){
    int rp = incl[i] - cnt[i] + partials[i>>8];
    row_ptr[i] = rp;
    pos[i] = rp;
  }
  if (i == E) row_ptr[E] = T;
}
__global__ void scatter_kernel(const int* __restrict__ e_to, int* __restrict__ pos,
                               int* __restrict__ perm, int T){
  int i = blockIdx.x*256 + threadIdx.x;
  if (i < T){
    int p = atomicAdd(&pos[e_to[i]], 1);
    perm[p] = i;
  }
}

// ---------------- edge: x_kj -> ws (f16), x_ji -> d_out (f32) ----------------
__global__ __launch_bounds__(256,2) void edge_kernel(
    const float* __restrict__ x,
    const float* __restrict__ radial,
    const float* __restrict__ w_rbf,
    const _Float16* __restrict__ wf,
    const float* __restrict__ b_from,
    const float* __restrict__ b_to,
    _Float16* __restrict__ x_kj, float* __restrict__ agg, int E)
{
  __shared__ alignas(16) _Float16 sA[64*LDA];
  __shared__ alignas(16) _Float16 sB[WFRAG];
  __shared__ alignas(16) _Float16 sO[64*LDA];
  __shared__ float sRad[64*8];
  __shared__ float sWr[128*8];
  __shared__ float sBf[128];
  __shared__ float sBt[128];
  int tid = threadIdx.x;
  int e0 = blockIdx.x*64;
  int wave = tid>>6, lane = tid&63, l15 = lane&15, q = lane>>4;

  const uint4* wfu = reinterpret_cast<const uint4*>(wf);
  const uint4* wtu = reinterpret_cast<const uint4*>(wf + WFRAG);
  uint4* sBu = reinterpret_cast<uint4*>(sB);
  uint4 wr[8];
  #pragma unroll
  for (int i=0;i<8;i++) wr[i] = wfu[i*256 + tid];

  {
    int row = tid>>2, cs = (tid&3)*32;
    bool ok = (e0+row) < E;
    const float4* src = reinterpret_cast<const float4*>(x + (size_t)(e0+row)*H + cs);
    #pragma unroll
    for (int i=0;i<4;i++){
      float4 u0{0,0,0,0}, u1{0,0,0,0};
      if (ok){ u0 = src[2*i]; u1 = src[2*i+1]; }
      *reinterpret_cast<f16x8*>(&sA[row*LDA + cs + i*8]) = pack8(u0,u1);
    }
  }
  for (int i=tid; i<64*NR; i+=256){
    int r=i/NR, c=i%NR;
    sRad[r*8+c] = (e0+r < E) ? radial[(size_t)(e0+r)*NR + c] : 0.f;
  }
  for (int i=tid; i<NR*H; i+=256){
    int c=i>>7, n=i&127;
    sWr[n*8+c] = w_rbf[i];
  }
  if (tid < H){ sBf[tid] = b_from[tid]; sBt[tid] = b_to[tid]; }
  #pragma unroll
  for (int i=0;i<8;i++) sBu[i*256 + tid] = wr[i];
  #pragma unroll
  for (int i=0;i<8;i++) wr[i] = wtu[i*256 + tid];
  __syncthreads();

  f32x4 acc[8];
  auto gemm = [&](){
    #pragma unroll
    for (int nt=0;nt<8;nt++) acc[nt] = f32x4{0.f,0.f,0.f,0.f};
    int ar = (wave*16 + l15)*LDA;
    #pragma unroll
    for (int kk=0;kk<4;kk++){
      f16x8 a = *reinterpret_cast<const f16x8*>(&sA[ar + kk*32 + q*8]);
      #pragma unroll
      for (int nt=0;nt<8;nt++){
        f16x8 b = *reinterpret_cast<const f16x8*>(&sB[((nt*4+kk)*64 + lane)*8]);
        acc[nt] = __builtin_amdgcn_mfma_f32_16x16x32_f16(a, b, acc[nt], 0,0,0);
      }
    }
  };

  gemm();  // x @ w_from
  __syncthreads();
  #pragma unroll
  for (int nt=0;nt<8;nt++)
    #pragma unroll
    for (int r=0;r<4;r++){
      int rl = wave*16 + q*4 + r, col = nt*16 + l15;
      float v = silu_f(acc[nt][r] + sBf[col]);
      float rb = 0.f;
      #pragma unroll
      for (int c=0;c<NR;c++) rb += sRad[rl*8+c]*sWr[col*8+c];
      sO[rl*LDA+col] = (_Float16)(v*rb);
    }
  #pragma unroll
  for (int i=0;i<8;i++) sBu[i*256 + tid] = wr[i];
  __syncthreads();
  {
    int row=tid>>2, cs=(tid&3)*32;
    if (e0+row < E)
      #pragma unroll
      for (int i=0;i<4;i++)
        *reinterpret_cast<f16x8*>(x_kj + (size_t)(e0+row)*H + cs + i*8) =
          *reinterpret_cast<const f16x8*>(&sO[row*LDA + cs + i*8]);
  }
  gemm();  // x @ w_to
  __syncthreads();
  #pragma unroll
  for (int nt=0;nt<8;nt++)
    #pragma unroll
    for (int r=0;r<4;r++){
      int rl = wave*16 + q*4 + r, col = nt*16 + l15;
      sO[rl*LDA+col] = (_Float16)silu_f(acc[nt][r] + sBt[col]);
    }
  __syncthreads();
  {
    int row=tid>>2, cs=(tid&3)*32;
    if (e0+row < E)
      #pragma unroll
      for (int i=0;i<4;i++){
        f16x8 v = *reinterpret_cast<const f16x8*>(&sO[row*LDA + cs + i*8]);
        float4 lo{(float)v[0],(float)v[1],(float)v[2],(float)v[3]};
        float4 hi{(float)v[4],(float)v[5],(float)v[6],(float)v[7]};
        float4* dp = reinterpret_cast<float4*>(agg + (size_t)(e0+row)*H + cs + i*8);
        dp[0] = lo; dp[1] = hi;
      }
  }
}

// ---------------- bilinear CSR: block owns 64 dst edges, atomic-free ----------------
struct PF {
  int valid;
  int dst;
  f16x8 sv;
  f16x8 g[8];
};

__global__ __launch_bounds__(256,2) void bilinear_csr_kernel(
    const _Float16* __restrict__ x_kj,
    const _Float16* __restrict__ sbf16,
    const _Float16* __restrict__ Wf,
    const int* __restrict__ e_from, const int* __restrict__ e_to,
    const int* __restrict__ perm, const int* __restrict__ row_ptr,
    float* __restrict__ agg, int E)
{
  __shared__ alignas(16) _Float16 gth[128*LDA];   // 34816 B
  __shared__ float accS[64*LDF];                  // 33792 B
  __shared__ float ssb[128*NB];                   // 4096 B
  __shared__ int sldst[128];                      // 512 B
  int tid = threadIdx.x;
  int e0 = blockIdx.x*64;
  int row = tid>>1, sub = tid&1;
  int wave = tid>>6, lane = tid&63, l15 = lane&15, q = lane>>4;
  int m0 = wave*32;

  int rp0 = row_ptr[e0];
  int e1 = e0 + 64; if (e1 > E) e1 = E;
  int rp1 = row_ptr[e1];

  for (int i=tid; i<64*LDF; i+=256) accS[i] = 0.f;

  // register prefetch of one chunk's gather data (perm -> e_from/e_to -> x_kj/sbf)
  auto prefetch = [&](int base) -> PF {
    PF o;
    int t = base + row;
    o.valid = (t < rp1);
    if (o.valid){
      int p = perm[t];
      int ef = e_from[p];
      o.dst = e_to[p] - e0;
      o.sv = *reinterpret_cast<const f16x8*>(sbf16 + (size_t)p*NB);
      const f16x8* gp = reinterpret_cast<const f16x8*>(x_kj + (size_t)ef*H + sub*64);
      #pragma unroll
      for (int i=0;i<8;i++) o.g[i] = gp[i];
    } else {
      o.dst = -1;
      #pragma unroll
      for (int j=0;j<8;j++) o.sv[j] = (_Float16)0.f;
      #pragma unroll
      for (int i=0;i<8;i++) o.g[i] = o.sv;
    }
    return o;
  };

  PF cur = prefetch(rp0);

  for (int base = rp0; base < rp1; base += 128){
    __syncthreads();   // prev chunk MFMA gth reads done; accS zero visible (iter 0)
    { // stage from prefetched regs (pure LDS writes)
      f16x8* gp = reinterpret_cast<f16x8*>(&gth[row*LDA + sub*64]);
      #pragma unroll
      for (int i=0;i<8;i++) gp[i] = cur.g[i];
      if (sub == 0){
        sldst[row] = cur.dst;
        #pragma unroll
        for (int j=0;j<NB;j++) ssb[row*NB + j] = (float)cur.sv[j];
      }
    }
    __syncthreads();   // staged visible
    // issue next chunk's prefetch NOW: loads fly under the MFMA below and are
    // drained at the next loop-top barrier (cheap), not before MFMA.
    PF nxt = prefetch(base + 128);

    f32x4 acc[2][8];
    #pragma unroll
    for (int mt=0;mt<2;mt++)
      #pragma unroll
      for (int nt=0;nt<8;nt++) acc[mt][nt] = f32x4{0.f,0.f,0.f,0.f};

    #pragma unroll
    for (int jj=0;jj<NB;jj++){
      const _Float16* wp = Wf + (size_t)jj*WFRAG;
      _Float16 s0 = (_Float16)ssb[(m0+l15)*NB + jj];
      _Float16 s1 = (_Float16)ssb[(m0+16+l15)*NB + jj];
      #pragma unroll
      for (int kk=0;kk<4;kk++){
        f16x8 a0 = *reinterpret_cast<const f16x8*>(&gth[(m0+l15)*LDA + kk*32 + q*8]);
        f16x8 a1 = *reinterpret_cast<const f16x8*>(&gth[(m0+16+l15)*LDA + kk*32 + q*8]);
        a0 *= s0; a1 *= s1;
        #pragma unroll
        for (int nt=0;nt<8;nt++){
          f16x8 b = *reinterpret_cast<const f16x8*>(wp + ((nt*4+kk)*64 + lane)*8);
          acc[0][nt] = __builtin_amdgcn_mfma_f32_16x16x32_f16(a0, b, acc[0][nt], 0,0,0);
          acc[1][nt] = __builtin_amdgcn_mfma_f32_16x16x32_f16(a1, b, acc[1][nt], 0,0,0);
        }
      }
    }
    // LDS accumulation (ds_add_f32, no global atomics)
    #pragma unroll
    for (int mt=0;mt<2;mt++)
      #pragma unroll
      for (int nt=0;nt<8;nt++)
        #pragma unroll
        for (int r=0;r<4;r++){
          int d = sldst[m0 + mt*16 + q*4 + r];
          if (d >= 0)
            atomicAdd(&accS[d*LDF + nt*16 + l15], acc[mt][nt][r]);
        }
    cur = nxt;
  }
  __syncthreads();
  { // out = x_ji (already in agg) + accS, plain coalesced f32 store
    int r2 = tid>>2, cs = (tid&3)*32;
    if (e0 + r2 < E){
      float4* dp = reinterpret_cast<float4*>(agg + (size_t)(e0+r2)*H + cs);
      #pragma unroll
      for (int i=0;i<8;i++){
        float4 a = dp[i];
        const float* s = &accS[r2*LDF + cs + i*4];
        a.x += s[0]; a.y += s[1]; a.z += s[2]; a.w += s[3];
        dp[i] = a;
      }
    }
  }
}

// ---------------- post: 64-row tiles, 7 GEMM stages ----------------
__global__ __launch_bounds__(256,3) void post_kernel(
    const float* __restrict__ x, const float* __restrict__ agg,
    const _Float16* __restrict__ wf,
    const float* __restrict__ rb_b, const float* __restrict__ lin_b,
    const float* __restrict__ ra_b,
    float* __restrict__ out, int E)
{
  __shared__ alignas(16) _Float16 smem[64*LDA + WFRAG];
  __shared__ float sBias[128];
  _Float16* sIn = smem;
  _Float16* sW  = smem + 64*LDA;
  uint4* sWu = reinterpret_cast<uint4*>(sW);
  int tid = threadIdx.x, e0 = blockIdx.x*64;
  int wave = tid>>6, lane = tid&63, l15 = lane&15, q = lane>>4;

  const float* bptr[7] = {rb_b, rb_b+128, lin_b, ra_b, ra_b+128, ra_b+256, ra_b+384};

  uint4 wr[8];
  {
    const uint4* wp = reinterpret_cast<const uint4*>(wf + 2*WFRAG);
    #pragma unroll
    for (int u=0;u<8;u++) wr[u] = wp[u*256 + tid];
  }

  {
    int row=tid>>2, cs=(tid&3)*32;
    bool ok = (e0+row) < E;
    const float4* ap = reinterpret_cast<const float4*>(agg + (size_t)(e0+row)*H + cs);
    #pragma unroll
    for (int i=0;i<4;i++){
      float4 u0{0,0,0,0}, u1{0,0,0,0};
      if (ok){ u0 = ap[2*i]; u1 = ap[2*i+1]; }
      *reinterpret_cast<f16x8*>(&sIn[row*LDA + cs + i*8]) = pack8(u0,u1);
    }
  }
  __syncthreads();
  float h[8][4];
  #pragma unroll
  for (int nt=0;nt<8;nt++)
    #pragma unroll
    for (int r=0;r<4;r++)
      h[nt][r] = (float)sIn[(wave*16+q*4+r)*LDA + nt*16 + l15];

  f32x4 acc[8];
  #pragma unroll
  for (int s=0;s<7;s++){
    #pragma unroll
    for (int u=0;u<8;u++) sWu[u*256 + tid] = wr[u];
    if (tid < H) sBias[tid] = bptr[s][tid];
    if (s < 6){
      const uint4* wp = reinterpret_cast<const uint4*>(wf + (size_t)(3+s)*WFRAG);
      #pragma unroll
      for (int u=0;u<8;u++) wr[u] = wp[u*256 + tid];
    }
    __syncthreads();
    #pragma unroll
    for (int nt=0;nt<8;nt++) acc[nt] = f32x4{0.f,0.f,0.f,0.f};
    int ar = (wave*16 + l15)*LDA;
    #pragma unroll
    for (int kk=0;kk<4;kk++){
      f16x8 a = *reinterpret_cast<const f16x8*>(&sIn[ar + kk*32 + q*8]);
      #pragma unroll
      for (int nt=0;nt<8;nt++){
        f16x8 b = *reinterpret_cast<const f16x8*>(&sW[((nt*4+kk)*64 + lane)*8]);
        acc[nt] = __builtin_amdgcn_mfma_f32_16x16x32_f16(a, b, acc[nt], 0,0,0);
      }
    }
    __syncthreads();
    #pragma unroll
    for (int nt=0;nt<8;nt++)
      #pragma unroll
      for (int r=0;r<4;r++){
        int rl = wave*16 + q*4 + r, col = nt*16 + l15;
        float v = silu_f(acc[nt][r] + sBias[col]);
        if (s==0 || s==3 || s==5){
          sIn[rl*LDA+col] = (_Float16)v;
        } else if (s==1 || s==4){
          h[nt][r] += v;
          sIn[rl*LDA+col] = (_Float16)h[nt][r];
        } else if (s==2){
          bool ok = (e0+rl) < E;
          float xv = ok ? x[(size_t)(e0+rl)*H + col] : 0.f;
          h[nt][r] = v + xv;
          sIn[rl*LDA+col] = (_Float16)h[nt][r];
        } else {
          h[nt][r] += v;
          reinterpret_cast<float*>(smem)[rl*LDF+col] = h[nt][r];
        }
      }
  }
  __syncthreads();
  {
    const float* scr = reinterpret_cast<const float*>(smem);
    int row=tid>>2, cs=(tid&3)*32;
    if (e0+row < E)
      #pragma unroll
      for (int i=0;i<8;i++)
        *reinterpret_cast<float4*>(out + (size_t)(e0+row)*H + cs + i*4) =
          *reinterpret_cast<const float4*>(&scr[row*LDF + cs + i*4]);
  }
}

extern "C" void kernel_launch(void* const* d_in, const int* in_sizes, int n_in,
                              void* d_out, int out_size, void* d_ws, size_t ws_size,
                              hipStream_t stream)
{
  const float* x      = (const float*)d_in[0];
  const float* radial = (const float*)d_in[1];
  const float* sph    = (const float*)d_in[2];
  const int* e_from   = (const int*)d_in[3];
  const int* e_to     = (const int*)d_in[4];
  const float* w_rbf  = (const float*)d_in[5];
  const float* w_sbf  = (const float*)d_in[6];
  const float* w_from = (const float*)d_in[7];
  const float* b_from = (const float*)d_in[8];
  const float* w_to   = (const float*)d_in[9];
  const float* b_to   = (const float*)d_in[10];
  const float* Wb     = (const float*)d_in[11];
  const float* rb_w   = (const float*)d_in[12];
  const float* rb_b   = (const float*)d_in[13];
  const float* lin_w  = (const float*)d_in[14];
  const float* lin_b  = (const float*)d_in[15];
  const float* ra_w   = (const float*)d_in[16];
  const float* ra_b   = (const float*)d_in[17];

  int E = in_sizes[0] / H;      // 100000
  int T = in_sizes[3];          // 262144
  int nE   = (E + 255) / 256;   // 391 blocks over edges
  int Epad = nE * 256;          // 100096
  int nT   = (T + 255) / 256;   // 1024

  float* agg = (float*)d_out;   // x_ji + msg-sum, in place

  char* ws = (char*)d_ws;
  size_t off = 0;
  auto alloc = [&](size_t bytes){ size_t o = off; off = (off + bytes + 255) & ~(size_t)255; return (void*)(ws + o); };
  _Float16* x_kj  = (_Float16*)alloc((size_t)E*H*2);        // 25.6 MB
  _Float16* wf    = (_Float16*)alloc((size_t)9*WFRAG*2);    // 288 KB
  _Float16* Wf    = (_Float16*)alloc((size_t)8*WFRAG*2);    // 256 KB
  _Float16* sbf16 = (_Float16*)alloc((size_t)T*NB*2);       // 4.2 MB
  int* cnt      = (int*)alloc((size_t)Epad*4);
  int* incl     = (int*)alloc((size_t)Epad*4);
  int* row_ptr  = (int*)alloc((size_t)Epad*4);
  int* pos      = (int*)alloc((size_t)E*4);
  int* perm     = (int*)alloc((size_t)T*4);
  int* partials = (int*)alloc(512*4);

  prep_kernel<<<136, 256, 0, stream>>>(w_from, w_to, rb_w, lin_w, ra_w, Wb, wf, Wf);
  sbf16_kernel<<<nT, 256, 0, stream>>>(sph, w_sbf, sbf16, T);
  zero_kernel<<<nE, 256, 0, stream>>>(cnt, Epad);
  hist_kernel<<<nT, 256, 0, stream>>>(e_to, cnt, T);
  scan1_kernel<<<nE, 256, 0, stream>>>(cnt, incl, partials, Epad);
  scan2_kernel<<<1, 512, 0, stream>>>(partials, nE);
  scan3_kernel<<<nE, 256, 0, stream>>>(incl, cnt, partials, row_ptr, pos, E, T);
  scatter_kernel<<<nT, 256, 0, stream>>>(e_to, pos, perm, T);
  edge_kernel<<<(E+63)/64, 256, 0, stream>>>(x, radial, w_rbf, wf, b_from, b_to,
                                             x_kj, agg, E);
  bilinear_csr_kernel<<<(E+63)/64, 256, 0, stream>>>(x_kj, sbf16, Wf, e_from, e_to,
                                                     perm, row_ptr, agg, E);
  post_kernel<<<(E+63)/64, 256, 0, stream>>>(x, agg, wf, rb_b, lin_b, ra_b,
                                             (float*)d_out, E);
}